// Round 1
// baseline (167.454 us; speedup 1.0000x reference)
//
#include <hip/hip_runtime.h>
#include <hip/hip_bf16.h>

#define B_DIM 8192
#define D_DIM 256
#define GRID_GEMM 512
#define NT 16   // 32-col tiles per block (512 cols per block)

constexpr float INV_T = 14.285714285714286f;   // 1/0.07; also the logsumexp shift M

typedef __bf16 bf16x8 __attribute__((ext_vector_type(8)));
typedef float  f32x16 __attribute__((ext_vector_type(16)));

#define GLOBAL_U32(p) ((const __attribute__((address_space(1))) unsigned int*)(p))
#define LDS_U32(p)    ((__attribute__((address_space(3))) unsigned int*)(p))

// s_waitcnt imm (gfx9): vm[3:0]=bits3:0, exp=bits6:4, lgkm=bits11:8, vm[5:4]=bits15:14
// vmcnt(8), expcnt/lgkmcnt = no-wait:
#define WAITCNT_VM8 0x0F78

__device__ inline unsigned short f2bf(float f) {
    union { float f; unsigned u; } x; x.f = f;
    unsigned r = x.u + 0x7fffu + ((x.u >> 16) & 1u);  // RNE
    return (unsigned short)(r >> 16);
}

// Kernel 1: q = normalize(h+r), t = normalize(t) -> bf16 workspace.
// 1024 blocks x 4 row-tasks per wave (was 4096 tiny blocks - dispatch hygiene).
// Block 0 additionally zeroes rowsum/diagsum/ticket.
__global__ __launch_bounds__(256) void norm_kernel(
    const float* __restrict__ h, const float* __restrict__ r,
    const float* __restrict__ t,
    unsigned short* __restrict__ qws, unsigned short* __restrict__ tws,
    float* __restrict__ rowsum, float* __restrict__ diagsum, int* __restrict__ ticket)
{
    if (blockIdx.x == 0) {
        float4* rs4 = (float4*)rowsum;
#pragma unroll
        for (int i = 0; i < 8; ++i)
            rs4[threadIdx.x * 8 + i] = make_float4(0.f, 0.f, 0.f, 0.f);
        if (threadIdx.x == 0) { *diagsum = 0.f; *ticket = 0; }
    }

    const int wave = threadIdx.x >> 6;
    const int lane = threadIdx.x & 63;
    const int wid  = blockIdx.x * 4 + wave;      // 0..4095

#pragma unroll
    for (int k = 0; k < 4; ++k) {
        const bool isQ = (k < 2);                 // k=0,1 -> q rows; k=2,3 -> t rows
        const int row = wid + (k & 1) * 4096;     // 0..8191

        float4 v;
        if (isQ) {
            float4 a = ((const float4*)h)[row * 64 + lane];
            float4 b = ((const float4*)r)[row * 64 + lane];
            v = make_float4(a.x + b.x, a.y + b.y, a.z + b.z, a.w + b.w);
        } else {
            v = ((const float4*)t)[row * 64 + lane];
        }
        float s = v.x * v.x + v.y * v.y + v.z * v.z + v.w * v.w;
#pragma unroll
        for (int off = 32; off; off >>= 1) s += __shfl_xor(s, off, 64);
        float scale = 1.0f / fmaxf(sqrtf(s), 1e-12f);

        ushort4 o;
        o.x = f2bf(v.x * scale);
        o.y = f2bf(v.y * scale);
        o.z = f2bf(v.z * scale);
        o.w = f2bf(v.w * scale);
        ushort4* dst = (ushort4*)(isQ ? qws : tws);
        dst[row * 64 + lane] = o;
    }
}

// Kernel 2: A-in-registers streaming GEMM, software-pipelined with RAW
// s_barrier + s_waitcnt vmcnt(8) (no vmcnt(0) drain). NEW vs previous version:
// the exp epilogue of round nt-1 is DEFERRED into round nt's MFMA scheduling
// region (T15 double-pipeline, two named acc sets e/o, unroll-by-2), so the
// transcendental VALU fills the MFMA chain-latency bubbles instead of sitting
// serially on each round's tail; MFMA+epi cluster wrapped in s_setprio(1/0).
__global__ __launch_bounds__(256, 2) void gemm_lse_kernel(
    const unsigned char* __restrict__ qws, const unsigned char* __restrict__ tws,
    float* __restrict__ rowsum, float* __restrict__ diagsum,
    int* __restrict__ ticket, float* __restrict__ out)
{
    __shared__ __align__(16) unsigned char ldsB[4][32 * 512];   // 64 KB
    __shared__ float wred[4];
    __shared__ int lastflag;

    const int tid  = threadIdx.x;
    const int lane = tid & 63;
    const int w    = tid >> 6;
    const int l31  = lane & 31;
    const int hi   = lane >> 5;

    const int cc   = blockIdx.x & 15;        // col chunk (fast -> XCD locality)
    const int rb   = blockIdx.x >> 4;        // row block 0..31
    const int row0 = rb * 256 + w * 64;      // this wave's 64 rows (distinct per wave)
    const int col0 = cc * 512;

    // ---- staging map: slot s -> row n = s>>5, phys chunk p = s&31,
    //      logical chunk kc = p ^ (n&7); global ofs = n*512 + kc*16 ----
    int srel[4];
#pragma unroll
    for (int it = 0; it < 4; ++it) {
        int s = it * 256 + tid;
        int n = s >> 5;
        int kc = (s & 31) ^ (n & 7);
        srel[it] = n * 512 + kc * 16;
    }

    // stage tile snt (32 cols x 512 B = 16 KB) into buffer bufi
#define STAGE(snt, bufi)                                                     \
    {                                                                        \
        const unsigned char* gs = tws + (size_t)(col0 + (snt) * 32) * 512;   \
        _Pragma("unroll")                                                    \
        for (int it = 0; it < 4; ++it)                                       \
            __builtin_amdgcn_global_load_lds(                                \
                GLOBAL_U32(gs + srel[it]),                                   \
                LDS_U32(&ldsB[bufi][(it * 256 + tid) * 16]), 16, 0, 0);      \
    }

    // prologue: tiles 0 and 1 in flight before the A-fragment loads
    STAGE(0, 0);
    STAGE(1, 1);

    // ---- A fragments in registers: rows row0..row0+63, full K=256 ----
    // 32x32x16 A layout: m = lane&31, k = ks*16 + hi*8 + j  (16B per frag)
    bf16x8 a[2][16];
    {
        const unsigned char* abase = qws + (size_t)(row0 + l31) * 512 + hi * 16;
#pragma unroll
        for (int rt = 0; rt < 2; ++rt)
#pragma unroll
            for (int ks = 0; ks < 16; ++ks)
                a[rt][ks] = *(const bf16x8*)(abase + rt * (32 * 512) + ks * 32);
    }

    f32x16 rowacc[2] = {};
    float diagacc = 0.f;
    const int nsw = l31 & 7;

    // Deferred epilogue for the accs of round ntp (P0=low 32 rows, P1=high).
#define EPI(ntp, P0, P1)                                                     \
    {                                                                        \
        _Pragma("unroll")                                                    \
        for (int g = 0; g < 16; ++g) {                                       \
            rowacc[0][g] += __expf(fmaf(P0[g], INV_T, -INV_T));              \
            rowacc[1][g] += __expf(fmaf(P1[g], INV_T, -INV_T));              \
        }                                                                    \
        const int c0p = col0 + (ntp) * 32;                                   \
        if (c0p == row0) {                                                   \
            _Pragma("unroll")                                                \
            for (int g = 0; g < 16; ++g) {                                   \
                const int rm = (g & 3) + 8 * (g >> 2) + 4 * hi;              \
                if (l31 == rm) diagacc += P0[g] * INV_T;                     \
            }                                                                \
        }                                                                    \
        if (c0p == row0 + 32) {                                              \
            _Pragma("unroll")                                                \
            for (int g = 0; g < 16; ++g) {                                   \
                const int rm = (g & 3) + 8 * (g >> 2) + 4 * hi;              \
                if (l31 == rm) diagacc += P1[g] * INV_T;                     \
            }                                                                \
        }                                                                    \
    }

    // One 32-col round: stage nt+2, wait tile nt (vmcnt(8): tiles nt+1,nt+2
    // stay in flight), barrier, MFMA into C0/C1, with EPIST (the previous
    // round's epilogue) placed INSIDE the same setprio region so the
    // scheduler interleaves its VALU with the MFMA chains.
#define ROUND(nt_, C0, C1, EPIST)                                            \
    {                                                                        \
        const int snt_ = ((nt_) + 2 < NT) ? (nt_) + 2 : NT - 1;              \
        STAGE(snt_, ((nt_) + 2) & 3);                                        \
        __builtin_amdgcn_s_waitcnt(WAITCNT_VM8);                             \
        __builtin_amdgcn_s_barrier();                                        \
        const unsigned char* bbuf_ = ldsB[(nt_) & 3];                        \
        C0 = (f32x16){};                                                     \
        C1 = (f32x16){};                                                     \
        __builtin_amdgcn_s_setprio(1);                                       \
        _Pragma("unroll")                                                    \
        for (int ks = 0; ks < 16; ++ks) {                                    \
            const int kc = ks * 2 + hi;                                      \
            bf16x8 b = *(const bf16x8*)(bbuf_ + l31 * 512 + ((kc ^ nsw) * 16)); \
            C0 = __builtin_amdgcn_mfma_f32_32x32x16_bf16(a[0][ks], b, C0, 0, 0, 0); \
            C1 = __builtin_amdgcn_mfma_f32_32x32x16_bf16(a[1][ks], b, C1, 0, 0, 0); \
        }                                                                    \
        EPIST;                                                               \
        __builtin_amdgcn_s_setprio(0);                                       \
    }

    // unroll-by-2 with named acc sets: even rounds -> e, odd rounds -> o
    f32x16 e0, e1, o0, o1;
    ROUND(0, e0, e1, (void)0);
#pragma unroll 1
    for (int p = 0; p < 7; ++p) {
        const int nt = 1 + 2 * p;                 // 1,3,...,13
        ROUND(nt,     o0, o1, EPI(nt - 1, e0, e1));
        ROUND(nt + 1, e0, e1, EPI(nt,     o0, o1));
    }
    ROUND(15, o0, o1, EPI(14, e0, e1));
    EPI(15, o0, o1);

    // ---- once per block: reduce across the 32 column-lanes, then atomics ----
#pragma unroll
    for (int rt = 0; rt < 2; ++rt)
#pragma unroll
        for (int g = 0; g < 16; ++g) {
            float s = (rt == 0) ? rowacc[0][g] : rowacc[1][g];
            s += __shfl_xor(s, 1, 64);
            s += __shfl_xor(s, 2, 64);
            s += __shfl_xor(s, 4, 64);
            s += __shfl_xor(s, 8, 64);
            s += __shfl_xor(s, 16, 64);
            if (l31 == 0) {
                int grow = row0 + rt * 32 + (g & 3) + 8 * (g >> 2) + 4 * hi;
                atomicAdd(&rowsum[grow], s);
            }
        }

    float dsum = diagacc;
#pragma unroll
    for (int off = 32; off; off >>= 1) dsum += __shfl_xor(dsum, off, 64);
    if (lane == 0 && dsum != 0.f) atomicAdd(diagsum, dsum);

    // ---- ticket: last block computes the loss ----
    __syncthreads();
    if (tid == 0) {
        __threadfence();
        int old = __hip_atomic_fetch_add(ticket, 1, __ATOMIC_ACQ_REL,
                                         __HIP_MEMORY_SCOPE_AGENT);
        lastflag = (old == GRID_GEMM - 1);
    }
    __syncthreads();
    if (!lastflag) return;

    float lsum = 0.f;
    for (int rr = tid; rr < B_DIM; rr += 256) {
        float rs = __hip_atomic_load(&rowsum[rr], __ATOMIC_RELAXED,
                                     __HIP_MEMORY_SCOPE_AGENT);
        lsum += __logf(rs);
    }
#pragma unroll
    for (int off = 32; off; off >>= 1) lsum += __shfl_xor(lsum, off, 64);
    if (lane == 0) wred[w] = lsum;
    __syncthreads();
    if (tid == 0) {
        float ds = __hip_atomic_load(diagsum, __ATOMIC_RELAXED,
                                     __HIP_MEMORY_SCOPE_AGENT);
        float total = wred[0] + wred[1] + wred[2] + wred[3]
                    + (float)B_DIM * INV_T   // + M per row
                    - ds;                    // - positive logits
        out[0] = total / (float)B_DIM;
    }
}

extern "C" void kernel_launch(void* const* d_in, const int* in_sizes, int n_in,
                              void* d_out, int out_size, void* d_ws, size_t ws_size,
                              hipStream_t stream)
{
    const float* h = (const float*)d_in[0];
    const float* r = (const float*)d_in[1];
    const float* t = (const float*)d_in[2];

    unsigned char* ws = (unsigned char*)d_ws;
    unsigned short* qws = (unsigned short*)ws;                        // 4 MB
    unsigned short* tws = (unsigned short*)(ws + 4u * 1024 * 1024);   // 4 MB
    float* rowsum  = (float*)(ws + 8u * 1024 * 1024);                 // 32 KB
    float* diagsum = (float*)(ws + 8u * 1024 * 1024 + 32u * 1024);
    int*   ticket  = (int*)  (ws + 8u * 1024 * 1024 + 32u * 1024 + 16);

    norm_kernel<<<1024, 256, 0, stream>>>(h, r, t, qws, tws, rowsum, diagsum, ticket);
    gemm_lse_kernel<<<GRID_GEMM, 256, 0, stream>>>(
        (const unsigned char*)qws, (const unsigned char*)tws,
        rowsum, diagsum, ticket, (float*)d_out);
}